// Round 4
// baseline (185.119 us; speedup 1.0000x reference)
//
#include <hip/hip_runtime.h>
#include <hip/hip_bf16.h>
#include <math.h>

#define S_LEN 2048
#define BSZ 2
#define DM 512
#define NH 8
#define HD 64
#define RTOT (S_LEN*BSZ)             // 4096 rows, row r = s*BSZ + b
#define T_KEEP 32
#define ROW0 ((S_LEN - T_KEEP)*BSZ)  // 4032
#define NXELEM (RTOT*DM)             // 2097152
#define NWROW  (NH*192)              // 1536
#define NWELEM (NWROW*DM)            // 786432

typedef __attribute__((ext_vector_type(8))) short short8;
typedef __attribute__((ext_vector_type(4))) float floatx4;

__device__ __forceinline__ void gld16(const void* g, void* l) {
    __builtin_amdgcn_global_load_lds((const __attribute__((address_space(1))) void*)g,
                                     (__attribute__((address_space(3))) void*)l, 16, 0, 0);
}

__device__ __forceinline__ void cvt2(float v, short& hs, short& ls) {
    __hip_bfloat16 h = __float2bfloat16(v);
    float hf = __bfloat162float(h);
    __hip_bfloat16 l = __float2bfloat16(v - hf);
    hs = __builtin_bit_cast(short, h);
    ls = __builtin_bit_cast(short, l);
}

// ------------- Kernel 0: fp32 -> bf16 hi/lo planes + bias concat + gbar zero ---
__global__ __launch_bounds__(256) void convert(
    const float* __restrict__ x,
    const float* __restrict__ Wq, const float* __restrict__ Wk, const float* __restrict__ Wv,
    const float* __restrict__ bq, const float* __restrict__ bk, const float* __restrict__ bv,
    short* __restrict__ xh, short* __restrict__ xl,
    short* __restrict__ wh, short* __restrict__ wl, float* __restrict__ bcat,
    float* __restrict__ gbar)
{
    const int g = blockIdx.x*blockDim.x + threadIdx.x;
    const int stride = gridDim.x*blockDim.x;
    const int total4 = (NXELEM + NWELEM)/4;
    for (int i = g; i < total4; i += stride) {
        float4 v; size_t dst;
        short* dh; short* dl;
        if (i < NXELEM/4) {
            v = ((const float4*)x)[i];
            dst = (size_t)i*4; dh = xh; dl = xl;
        } else {
            int j = i - NXELEM/4;
            int e = j*4;
            int R = e >> 9;
            int k = e & 511;
            int hh = R / 192; int rem = R - hh*192; int m = rem >> 6; int c = rem & 63;
            const float* W = (m == 0 ? Wq : (m == 1 ? Wk : Wv));
            v = *(const float4*)&W[(size_t)(hh*HD + c)*DM + k];
            dst = (size_t)R*DM + k; dh = wh; dl = wl;
        }
        short4 hv, lv;
        cvt2(v.x, hv.x, lv.x); cvt2(v.y, hv.y, lv.y);
        cvt2(v.z, hv.z, lv.z); cvt2(v.w, hv.w, lv.w);
        *(short4*)&dh[dst] = hv;
        *(short4*)&dl[dst] = lv;
    }
    if (g < NWROW) {
        int hh = g / 192, rem = g - hh*192, m = rem >> 6, c = rem & 63;
        bcat[g] = (m == 0 ? bq : (m == 1 ? bk : bv))[hh*HD + c];
    }
    if (g < 2048) gbar[g] = 0.f;
}

// ------------- Kernel 1: MFMA split-bf16 qkv GEMM + sigma accumulation ---------
// grid (64, 8): block = 64 rows x head h's 192 cols. BK=64, 8 K-iterations.
// Waves 2x2: wave (rowg,colg) computes 32 rows x 96 cols.
// LDS (64KB single buffer): A_hi[8K] A_lo[8K] B_hi[24K] B_lo[24K], 1KB frag chunks.
__global__ __launch_bounds__(256) void qkv_gemm(
    const short* __restrict__ xh, const short* __restrict__ xl,
    const short* __restrict__ wh, const short* __restrict__ wl,
    const float* __restrict__ bcat, const float* __restrict__ beta,
    float* __restrict__ gbar, float* __restrict__ qsel)
{
    __shared__ __align__(16) char smem[65536];   // stage 64KB, then C dump 48KB
    __shared__ float sb[256];

    const int tid  = threadIdx.x;
    const int w    = tid >> 6;
    const int lane = tid & 63;
    const int lrow = lane & 15;
    const int lk8  = lane >> 4;
    const int h    = blockIdx.y;
    const int r0   = blockIdx.x * 64;
    const int rowg = w >> 1;
    const int colg = w & 1;

    floatx4 acc[2][6];
    #pragma unroll
    for (int i = 0; i < 2; ++i)
        #pragma unroll
        for (int j = 0; j < 6; ++j) acc[i][j] = (floatx4)0.f;

    // staging: wave w stages A-frag f=w (rows w*16..w*16+15) and B-frags 3w..3w+2
    const size_t aoff = (size_t)(r0 + w*16 + lrow)*DM + lk8*8;
    const size_t boff = (size_t)(h*192 + 3*w*16 + lrow)*DM + lk8*8;
    const short* asrc[2] = { xh + aoff, xl + aoff };
    const short* bsrc[2] = { wh + boff, wl + boff };

    for (int kc = 0; kc < 8; ++kc) {
        const int ko = kc*64;
        #pragma unroll
        for (int p = 0; p < 2; ++p) {
            #pragma unroll
            for (int kh = 0; kh < 2; ++kh) {
                gld16(asrc[p] + ko + kh*32, smem + p*8192 + (w*2 + kh)*1024);
                #pragma unroll
                for (int jj = 0; jj < 3; ++jj)
                    gld16(bsrc[p] + (size_t)jj*16*DM + ko + kh*32,
                          smem + 16384 + p*24576 + ((3*w + jj)*2 + kh)*1024);
            }
        }
        __syncthreads();
        #pragma unroll
        for (int kh = 0; kh < 2; ++kh) {
            short8 ah[2], al[2];
            #pragma unroll
            for (int i = 0; i < 2; ++i) {
                ah[i] = *(const short8*)(smem + ((rowg*2 + i)*2 + kh)*1024 + lane*16);
                al[i] = *(const short8*)(smem + 8192 + ((rowg*2 + i)*2 + kh)*1024 + lane*16);
            }
            #pragma unroll
            for (int j = 0; j < 6; ++j) {
                short8 bh = *(const short8*)(smem + 16384 + ((colg*6 + j)*2 + kh)*1024 + lane*16);
                short8 bl = *(const short8*)(smem + 40960 + ((colg*6 + j)*2 + kh)*1024 + lane*16);
                #pragma unroll
                for (int i = 0; i < 2; ++i) {
                    acc[i][j] = __builtin_amdgcn_mfma_f32_16x16x32_bf16(ah[i], bh, acc[i][j], 0, 0, 0);
                    acc[i][j] = __builtin_amdgcn_mfma_f32_16x16x32_bf16(al[i], bh, acc[i][j], 0, 0, 0);
                    acc[i][j] = __builtin_amdgcn_mfma_f32_16x16x32_bf16(ah[i], bl, acc[i][j], 0, 0, 0);
                }
            }
        }
        __syncthreads();
    }

    // dump C (+bias) to LDS (64 x 192 fp32 = 48KB, reuses stage region)
    float* Cl = (float*)smem;
    #pragma unroll
    for (int i = 0; i < 2; ++i) {
        #pragma unroll
        for (int j = 0; j < 6; ++j) {
            int col = colg*96 + j*16 + lrow;
            float bias = bcat[h*192 + col];
            #pragma unroll
            for (int reg = 0; reg < 4; ++reg) {
                int row = rowg*32 + i*16 + lk8*4 + reg;
                Cl[row*192 + col] = acc[i][j][reg] + bias;
            }
        }
    }
    sb[tid] = 0.f;
    __syncthreads();

    const float inv_scale = 1.0f / (8.0f * expf(beta[h]));
    float kacc0 = 0.f, kacc1 = 0.f, vacc0 = 0.f, vacc1 = 0.f;
    for (int i2 = w; i2 < 64; i2 += 4) {
        float qv = Cl[i2*192 + lane];
        float kv = Cl[i2*192 + 64 + lane];
        float vv = Cl[i2*192 + 128 + lane];
        int r = r0 + i2;
        int s = r >> 1;
        int b = r & 1;
        if ((s & 63) == 63) {
            int wi = s >> 6;
            qsel[((size_t)(b*NH + h)*T_KEEP + wi)*64 + lane] = qv;
        }
        float p = qv * kv;
        #pragma unroll
        for (int off = 32; off > 0; off >>= 1) p += __shfl_xor(p, off, 64);
        float sig = 1.0f / (1.0f + expf(-p * inv_scale));
        if (b == 0) { kacc0 += sig*kv; vacc0 += sig*vv; }
        else        { kacc1 += sig*kv; vacc1 += sig*vv; }
    }
    atomicAdd(&sb[  0 + lane], kacc0);
    atomicAdd(&sb[ 64 + lane], vacc0);
    atomicAdd(&sb[128 + lane], kacc1);
    atomicAdd(&sb[192 + lane], vacc1);
    __syncthreads();
    {
        int b   = tid >> 7;
        int sel = (tid >> 6) & 1;
        int j   = tid & 63;
        int z   = b*NH + h;
        atomicAdd(&gbar[sel*1024 + z*64 + j], sb[tid]);
    }
}

// ------------- Kernel 2: fused softmax + attn-row GEMM + background fill -------
// blocks 0..63: output row ROW0+a (a = wi*2+b): scores->softmax->arow->Wo GEMM.
// blocks 64..575: fill rows < ROW0 with bo.
__global__ __launch_bounds__(256) void outk(
    const float* __restrict__ qsel, const float* __restrict__ beta,
    const float* __restrict__ gbar, const float* __restrict__ Wo,
    const float* __restrict__ bo, float* __restrict__ out)
{
    const int tid = threadIdx.x;
    if (blockIdx.x >= 64) {
        int g = (blockIdx.x - 64)*256 + tid;
        const float4* b4 = (const float4*)bo;
        float4* o4 = (float4*)out;
        const int total4 = ROW0*DM/4;
        for (int i = g; i < total4; i += 512*256) o4[i] = b4[i & 127];
        return;
    }
    const int a = blockIdx.x;
    const int wi_blk = a >> 1;
    const int b = a & 1;
    const int w = tid >> 6;
    const int lane = tid & 63;

    __shared__ float s_sc[NH][T_KEEP];
    __shared__ float s_cw[NH];
    __shared__ float arow[DM];

    #pragma unroll
    for (int hh = 0; hh < 2; ++hh) {
        int h = w*2 + hh;
        int z = b*NH + h;
        float kb = gbar[z*64 + lane];
        for (int wi = 0; wi < T_KEEP; ++wi) {
            float p = qsel[((size_t)z*T_KEEP + wi)*64 + lane] * kb;
            #pragma unroll
            for (int off = 32; off > 0; off >>= 1) p += __shfl_xor(p, off, 64);
            if (lane == 0) s_sc[h][wi] = p;
        }
    }
    __syncthreads();
    if (tid < NH) {
        int h = tid;
        float inv_scale = 1.0f / (8.0f * expf(beta[h]));
        float mx = 0.f;  // sink score = 0
        for (int wi = 0; wi < T_KEEP; ++wi) mx = fmaxf(mx, s_sc[h][wi]*inv_scale);
        float denom = expf(-mx);
        for (int wi = 0; wi < T_KEEP; ++wi) denom += expf(s_sc[h][wi]*inv_scale - mx);
        float c = expf(s_sc[h][wi_blk]*inv_scale - mx) / denom;
        if (wi_blk == T_KEEP-1) c += 1.0f;
        s_cw[h] = c;
    }
    __syncthreads();
    for (int c = tid; c < DM; c += 256) {
        int h = c >> 6, j = c & 63;
        arow[c] = s_cw[h] * gbar[1024 + (b*NH + h)*64 + j];
    }
    __syncthreads();
    const int r = ROW0 + a;
    for (int c = tid; c < DM; c += 256) {
        const float* worow = &Wo[(size_t)c*DM];
        float accv = bo[c];
        for (int k = 0; k < DM; k += 4) {
            float4 a4 = *(const float4*)&arow[k];
            float4 w4 = *(const float4*)&worow[k];
            accv += a4.x*w4.x + a4.y*w4.y + a4.z*w4.z + a4.w*w4.w;
        }
        out[(size_t)r*DM + c] = accv;
    }
}

extern "C" void kernel_launch(void* const* d_in, const int* in_sizes, int n_in,
                              void* d_out, int out_size, void* d_ws, size_t ws_size,
                              hipStream_t stream) {
    const float* x    = (const float*)d_in[0];
    const float* Wq   = (const float*)d_in[1];
    const float* bq   = (const float*)d_in[2];
    const float* Wk   = (const float*)d_in[3];
    const float* bk   = (const float*)d_in[4];
    const float* Wv   = (const float*)d_in[5];
    const float* bv   = (const float*)d_in[6];
    const float* Wo   = (const float*)d_in[7];
    const float* bo   = (const float*)d_in[8];
    const float* beta = (const float*)d_in[9];

    char* ws = (char*)d_ws;
    float* gbar = (float*)(ws + 0);           //   8 KB
    float* qsel = (float*)(ws + 8192);        // 128 KB
    float* bcat = (float*)(ws + 139264);      //   6 KB
    short* xh   = (short*)(ws + 147456);      //   4 MB
    short* xl   = (short*)(ws + 147456 + 4194304);
    short* wh   = (short*)(ws + 147456 + 2*4194304);
    short* wl   = (short*)(ws + 147456 + 2*4194304 + 1572864);

    convert<<<1024, 256, 0, stream>>>(x, Wq, Wk, Wv, bq, bk, bv, xh, xl, wh, wl, bcat, gbar);
    dim3 g1(RTOT/64, NH);
    qkv_gemm<<<g1, 256, 0, stream>>>(xh, xl, wh, wl, bcat, beta, gbar, qsel);
    outk<<<576, 256, 0, stream>>>(qsel, beta, gbar, Wo, bo, (float*)d_out);
}

// Round 5
// 167.141 us; speedup vs baseline: 1.1076x; 1.1076x over previous
//
#include <hip/hip_runtime.h>
#include <hip/hip_bf16.h>
#include <math.h>

#define S_LEN 2048
#define BSZ 2
#define DM 512
#define NH 8
#define HD 64
#define RTOT (S_LEN*BSZ)             // 4096 rows, row r = s*BSZ + b
#define T_KEEP 32
#define ROW0 ((S_LEN - T_KEEP)*BSZ)  // 4032
#define NXELEM (RTOT*DM)             // 2097152
#define NWROW  (NH*192)              // 1536
#define NWELEM (NWROW*DM)            // 786432

typedef __attribute__((ext_vector_type(8))) short short8;
typedef __attribute__((ext_vector_type(4))) float floatx4;

__device__ __forceinline__ void gld16(const void* g, void* l) {
    __builtin_amdgcn_global_load_lds((const __attribute__((address_space(1))) void*)g,
                                     (__attribute__((address_space(3))) void*)l, 16, 0, 0);
}

__device__ __forceinline__ void cvt2(float v, short& hs, short& ls) {
    __hip_bfloat16 h = __float2bfloat16(v);
    float hf = __bfloat162float(h);
    __hip_bfloat16 l = __float2bfloat16(v - hf);
    hs = __builtin_bit_cast(short, h);
    ls = __builtin_bit_cast(short, l);
}

// ---- Kernel 0: fp32 -> bf16 hi/lo planes + bias concat + gbar zero + bg fill --
__global__ __launch_bounds__(256) void convert(
    const float* __restrict__ x,
    const float* __restrict__ Wq, const float* __restrict__ Wk, const float* __restrict__ Wv,
    const float* __restrict__ bq, const float* __restrict__ bk, const float* __restrict__ bv,
    const float* __restrict__ bo,
    short* __restrict__ xh, short* __restrict__ xl,
    short* __restrict__ wh, short* __restrict__ wl, float* __restrict__ bcat,
    float* __restrict__ gbar, float* __restrict__ out)
{
    const int g = blockIdx.x*blockDim.x + threadIdx.x;
    const int stride = gridDim.x*blockDim.x;
    const int total4 = (NXELEM + NWELEM)/4;
    for (int i = g; i < total4; i += stride) {
        float4 v; size_t dst;
        short* dh; short* dl;
        if (i < NXELEM/4) {
            v = ((const float4*)x)[i];
            dst = (size_t)i*4; dh = xh; dl = xl;
        } else {
            int j = i - NXELEM/4;
            int e = j*4;
            int R = e >> 9;
            int k = e & 511;
            int hh = R / 192; int rem = R - hh*192; int m = rem >> 6; int c = rem & 63;
            const float* W = (m == 0 ? Wq : (m == 1 ? Wk : Wv));
            v = *(const float4*)&W[(size_t)(hh*HD + c)*DM + k];
            dst = (size_t)R*DM + k; dh = wh; dl = wl;
        }
        short4 hv, lv;
        cvt2(v.x, hv.x, lv.x); cvt2(v.y, hv.y, lv.y);
        cvt2(v.z, hv.z, lv.z); cvt2(v.w, hv.w, lv.w);
        *(short4*)&dh[dst] = hv;
        *(short4*)&dl[dst] = lv;
    }
    // background fill: rows < ROW0 of out are just bo
    {
        const float4* b4 = (const float4*)bo;
        float4* o4 = (float4*)out;
        const int fill4 = ROW0*DM/4;
        for (int i = g; i < fill4; i += stride) o4[i] = b4[i & 127];
    }
    if (g < NWROW) {
        int hh = g / 192, rem = g - hh*192, m = rem >> 6, c = rem & 63;
        bcat[g] = (m == 0 ? bq : (m == 1 ? bk : bv))[hh*HD + c];
    }
    if (g < 2048) gbar[g] = 0.f;
}

// ------------- Kernel 1: MFMA split-bf16 qkv GEMM + sigma accumulation ---------
// grid (64, 8): block = 64 rows x head h's 192 cols. BK=64, 8 K-iterations.
__global__ __launch_bounds__(256) void qkv_gemm(
    const short* __restrict__ xh, const short* __restrict__ xl,
    const short* __restrict__ wh, const short* __restrict__ wl,
    const float* __restrict__ bcat, const float* __restrict__ beta,
    float* __restrict__ gbar, float* __restrict__ qsel)
{
    __shared__ __align__(16) char smem[65536];   // stage 64KB, then C dump 48KB
    __shared__ float sb[256];

    const int tid  = threadIdx.x;
    const int w    = tid >> 6;
    const int lane = tid & 63;
    const int lrow = lane & 15;
    const int lk8  = lane >> 4;
    const int h    = blockIdx.y;
    const int r0   = blockIdx.x * 64;
    const int rowg = w >> 1;
    const int colg = w & 1;

    floatx4 acc[2][6];
    #pragma unroll
    for (int i = 0; i < 2; ++i)
        #pragma unroll
        for (int j = 0; j < 6; ++j) acc[i][j] = (floatx4)0.f;

    const size_t aoff = (size_t)(r0 + w*16 + lrow)*DM + lk8*8;
    const size_t boff = (size_t)(h*192 + 3*w*16 + lrow)*DM + lk8*8;
    const short* asrc[2] = { xh + aoff, xl + aoff };
    const short* bsrc[2] = { wh + boff, wl + boff };

    for (int kc = 0; kc < 8; ++kc) {
        const int ko = kc*64;
        #pragma unroll
        for (int p = 0; p < 2; ++p) {
            #pragma unroll
            for (int kh = 0; kh < 2; ++kh) {
                gld16(asrc[p] + ko + kh*32, smem + p*8192 + (w*2 + kh)*1024);
                #pragma unroll
                for (int jj = 0; jj < 3; ++jj)
                    gld16(bsrc[p] + (size_t)jj*16*DM + ko + kh*32,
                          smem + 16384 + p*24576 + ((3*w + jj)*2 + kh)*1024);
            }
        }
        __syncthreads();
        #pragma unroll
        for (int kh = 0; kh < 2; ++kh) {
            short8 ah[2], al[2];
            #pragma unroll
            for (int i = 0; i < 2; ++i) {
                ah[i] = *(const short8*)(smem + ((rowg*2 + i)*2 + kh)*1024 + lane*16);
                al[i] = *(const short8*)(smem + 8192 + ((rowg*2 + i)*2 + kh)*1024 + lane*16);
            }
            #pragma unroll
            for (int j = 0; j < 6; ++j) {
                short8 bh = *(const short8*)(smem + 16384 + ((colg*6 + j)*2 + kh)*1024 + lane*16);
                short8 bl = *(const short8*)(smem + 40960 + ((colg*6 + j)*2 + kh)*1024 + lane*16);
                #pragma unroll
                for (int i = 0; i < 2; ++i) {
                    acc[i][j] = __builtin_amdgcn_mfma_f32_16x16x32_bf16(ah[i], bh, acc[i][j], 0, 0, 0);
                    acc[i][j] = __builtin_amdgcn_mfma_f32_16x16x32_bf16(al[i], bh, acc[i][j], 0, 0, 0);
                    acc[i][j] = __builtin_amdgcn_mfma_f32_16x16x32_bf16(ah[i], bl, acc[i][j], 0, 0, 0);
                }
            }
        }
        __syncthreads();
    }

    float* Cl = (float*)smem;
    #pragma unroll
    for (int i = 0; i < 2; ++i) {
        #pragma unroll
        for (int j = 0; j < 6; ++j) {
            int col = colg*96 + j*16 + lrow;
            float bias = bcat[h*192 + col];
            #pragma unroll
            for (int reg = 0; reg < 4; ++reg) {
                int row = rowg*32 + i*16 + lk8*4 + reg;
                Cl[row*192 + col] = acc[i][j][reg] + bias;
            }
        }
    }
    sb[tid] = 0.f;
    __syncthreads();

    const float inv_scale = 1.0f / (8.0f * expf(beta[h]));
    float kacc0 = 0.f, kacc1 = 0.f, vacc0 = 0.f, vacc1 = 0.f;
    for (int i2 = w; i2 < 64; i2 += 4) {
        float qv = Cl[i2*192 + lane];
        float kv = Cl[i2*192 + 64 + lane];
        float vv = Cl[i2*192 + 128 + lane];
        int r = r0 + i2;
        int s = r >> 1;
        int b = r & 1;
        if ((s & 63) == 63) {
            int wi = s >> 6;
            qsel[((size_t)(b*NH + h)*T_KEEP + wi)*64 + lane] = qv;
        }
        float p = qv * kv;
        #pragma unroll
        for (int off = 32; off > 0; off >>= 1) p += __shfl_xor(p, off, 64);
        float sig = 1.0f / (1.0f + expf(-p * inv_scale));
        if (b == 0) { kacc0 += sig*kv; vacc0 += sig*vv; }
        else        { kacc1 += sig*kv; vacc1 += sig*vv; }
    }
    atomicAdd(&sb[  0 + lane], kacc0);
    atomicAdd(&sb[ 64 + lane], vacc0);
    atomicAdd(&sb[128 + lane], kacc1);
    atomicAdd(&sb[192 + lane], vacc1);
    __syncthreads();
    {
        int b   = tid >> 7;
        int sel = (tid >> 6) & 1;
        int j   = tid & 63;
        int z   = b*NH + h;
        atomicAdd(&gbar[sel*1024 + z*64 + j], sb[tid]);
    }
}

// ------------- Kernel 2: G[b][h][c'] = sum_j vbar[b,h,j] * Wo[c'][h*64+j] ------
// grid 128 x 256: one wave per c' (coalesced Wo reads, Wo read exactly once).
__global__ __launch_bounds__(256) void gmat(
    const float* __restrict__ gbar, const float* __restrict__ Wo,
    float* __restrict__ G)   // [2][8][512]
{
    const int tid = threadIdx.x;
    const int w = tid >> 6;
    const int lane = tid & 63;
    const int cp = blockIdx.x*4 + w;   // 0..511
    #pragma unroll
    for (int h = 0; h < NH; ++h) {
        float wv = Wo[(size_t)cp*DM + h*64 + lane];
        #pragma unroll
        for (int b = 0; b < 2; ++b) {
            float p = gbar[1024 + (b*NH + h)*64 + lane] * wv;
            #pragma unroll
            for (int off = 32; off > 0; off >>= 1) p += __shfl_xor(p, off, 64);
            if (lane == 0) G[(b*NH + h)*DM + cp] = p;
        }
    }
}

// ------------- Kernel 3: scores -> softmax coef -> out rows via G --------------
// grid 64: block a -> output row ROW0+a (a = wi*2 + b).
__global__ __launch_bounds__(256) void outk(
    const float* __restrict__ qsel, const float* __restrict__ beta,
    const float* __restrict__ gbar, const float* __restrict__ G,
    const float* __restrict__ bo, float* __restrict__ out)
{
    const int a = blockIdx.x;
    const int wi_blk = a >> 1;
    const int b = a & 1;
    const int tid = threadIdx.x;
    const int w = tid >> 6;
    const int lane = tid & 63;

    __shared__ float s_sc[NH][T_KEEP];
    __shared__ float s_cw[NH];

    #pragma unroll
    for (int hh = 0; hh < 2; ++hh) {
        int h = w*2 + hh;
        int z = b*NH + h;
        float kb = gbar[z*64 + lane];
        for (int wi = 0; wi < T_KEEP; ++wi) {
            float p = qsel[((size_t)z*T_KEEP + wi)*64 + lane] * kb;
            #pragma unroll
            for (int off = 32; off > 0; off >>= 1) p += __shfl_xor(p, off, 64);
            if (lane == 0) s_sc[h][wi] = p;
        }
    }
    __syncthreads();
    if (tid < NH) {
        int h = tid;
        float inv_scale = 1.0f / (8.0f * expf(beta[h]));
        float mx = 0.f;  // sink score = 0
        for (int wi = 0; wi < T_KEEP; ++wi) mx = fmaxf(mx, s_sc[h][wi]*inv_scale);
        float denom = expf(-mx);
        for (int wi = 0; wi < T_KEEP; ++wi) denom += expf(s_sc[h][wi]*inv_scale - mx);
        float c = expf(s_sc[h][wi_blk]*inv_scale - mx) / denom;
        if (wi_blk == T_KEEP-1) c += 1.0f;
        s_cw[h] = c;
    }
    __syncthreads();
    const int r = ROW0 + a;
    for (int c = tid; c < DM; c += 256) {
        float accv = bo[c];
        #pragma unroll
        for (int h = 0; h < NH; ++h)
            accv += s_cw[h] * G[(b*NH + h)*DM + c];
        out[(size_t)r*DM + c] = accv;
    }
}

extern "C" void kernel_launch(void* const* d_in, const int* in_sizes, int n_in,
                              void* d_out, int out_size, void* d_ws, size_t ws_size,
                              hipStream_t stream) {
    const float* x    = (const float*)d_in[0];
    const float* Wq   = (const float*)d_in[1];
    const float* bq   = (const float*)d_in[2];
    const float* Wk   = (const float*)d_in[3];
    const float* bk   = (const float*)d_in[4];
    const float* Wv   = (const float*)d_in[5];
    const float* bv   = (const float*)d_in[6];
    const float* Wo   = (const float*)d_in[7];
    const float* bo   = (const float*)d_in[8];
    const float* beta = (const float*)d_in[9];

    char* ws = (char*)d_ws;
    float* gbar = (float*)(ws + 0);           //   8 KB
    float* qsel = (float*)(ws + 8192);        // 128 KB
    float* bcat = (float*)(ws + 139264);      //   8 KB
    float* G    = (float*)(ws + 147456);      //  32 KB
    short* xh   = (short*)(ws + 180224);      //   4 MB
    short* xl   = (short*)(ws + 180224 + 4194304);
    short* wh   = (short*)(ws + 180224 + 2*4194304);
    short* wl   = (short*)(ws + 180224 + 2*4194304 + 1572864);
    float* out  = (float*)d_out;

    convert<<<1024, 256, 0, stream>>>(x, Wq, Wk, Wv, bq, bk, bv, bo,
                                      xh, xl, wh, wl, bcat, gbar, out);
    dim3 g1(RTOT/64, NH);
    qkv_gemm<<<g1, 256, 0, stream>>>(xh, xl, wh, wl, bcat, beta, gbar, qsel);
    gmat<<<128, 256, 0, stream>>>(gbar, Wo, G);
    outk<<<64, 256, 0, stream>>>(qsel, beta, gbar, G, bo, out);
}